// Round 1
// baseline (372.839 us; speedup 1.0000x reference)
//
#include <hip/hip_runtime.h>

#define BQ 4
#define SQ 2048
#define DQ 1024
#define HQ 16
#define BHQ 64

typedef __attribute__((ext_vector_type(8))) short short8;
typedef __attribute__((ext_vector_type(4))) float f32x4;
typedef unsigned short u16;
typedef unsigned int u32;

__device__ __forceinline__ u16 f2bf(float f) {
  u32 u = __float_as_uint(f);
  u32 r = u + 0x7fffu + ((u >> 16) & 1u);
  return (u16)(r >> 16);
}
__device__ __forceinline__ float bf2f(u16 h) {
  return __uint_as_float(((u32)h) << 16);
}

// async global->LDS, 16B per lane. LDS dest must be wave-uniform; HW adds lane*16.
__device__ __forceinline__ void gload_lds16(const void* g, void* l) {
  __builtin_amdgcn_global_load_lds(
      (const __attribute__((address_space(1))) u32*)(unsigned long long)g,
      (__attribute__((address_space(3))) u32*)(u32)(unsigned long long)l,
      16, 0, 0);
}

// ---------------- fp32 -> bf16 convert (vectorized) ----------------
__global__ __launch_bounds__(256) void k_cvt(const float* __restrict__ in, u16* __restrict__ out, int n4) {
  int i = blockIdx.x * 256 + threadIdx.x;
  if (i < n4) {
    float4 v = ((const float4*)in)[i];
    ushort4 o;
    o.x = f2bf(v.x); o.y = f2bf(v.y); o.z = f2bf(v.z); o.w = f2bf(v.w);
    ((ushort4*)out)[i] = o;
  }
}

// ---------------- transpose + convert: in[R][C] f32 -> out[C][R] bf16 ----------------
__global__ __launch_bounds__(256) void k_transpose_cvt(const float* __restrict__ in, u16* __restrict__ out,
                                                       int R, int C) {
  __shared__ float t[32][33];
  int c0 = blockIdx.x * 32, r0 = blockIdx.y * 32;
  int tx = threadIdx.x & 31, ty = threadIdx.x >> 5;
  for (int rr = ty; rr < 32; rr += 8)
    t[rr][tx] = in[(size_t)(r0 + rr) * C + c0 + tx];
  __syncthreads();
  for (int rr = ty; rr < 32; rr += 8)
    out[(size_t)(c0 + rr) * R + r0 + tx] = f2bf(t[tx][rr]);
}

// ---------------- RoPE cos/sin table [S][32][2] f32 ----------------
__global__ __launch_bounds__(256) void k_rope_table(float* __restrict__ tab) {
  int i = blockIdx.x * 256 + threadIdx.x;
  if (i >= SQ * 32) return;
  int s = i >> 5, dp = i & 31;
  // inv_freq = 10000^(-dp/32) = exp(-ln(10000)/32 * dp)
  float invf = expf(-0.28782313662425576f * (float)dp);
  float ang = (float)s * invf;
  tab[i * 2] = cosf(ang);
  tab[i * 2 + 1] = sinf(ang);
}

// ---------------- RoPE apply in-place on q (scaled by 1/8) and k ----------------
__global__ __launch_bounds__(256) void k_rope(u16* __restrict__ q, u16* __restrict__ k,
                                              const float* __restrict__ tab) {
  int i = blockIdx.x * 256 + threadIdx.x;
  const int half = BHQ * SQ * 32;
  u16* buf = (i < half) ? q : k;
  float scale = (i < half) ? 0.125f : 1.0f;
  int rem = (i < half) ? i : i - half;
  int r = rem >> 5, dp = rem & 31;
  int s = r & (SQ - 1);
  float c = tab[(s * 32 + dp) * 2], sn = tab[(s * 32 + dp) * 2 + 1];
  size_t base = (size_t)r * 64 + dp;
  float a = bf2f(buf[base]), b = bf2f(buf[base + 32]);
  buf[base] = f2bf((a * c - b * sn) * scale);
  buf[base + 32] = f2bf((b * c + a * sn) * scale);
}

// ---------------- transpose v [bh][S][64] -> vT [bh][64][S] ----------------
__global__ __launch_bounds__(256) void k_transpose_v(const u16* __restrict__ v, u16* __restrict__ vT) {
  __shared__ u16 t[64][72];
  int s0 = blockIdx.x * 64, bh = blockIdx.y;
  int tid = threadIdx.x;
  int row = tid >> 2, c0 = (tid & 3) * 16;
  const u16* src = v + ((size_t)bh * SQ + s0 + row) * 64 + c0;
  *(short8*)&t[row][c0] = *(const short8*)src;
  *(short8*)&t[row][c0 + 8] = *(const short8*)(src + 8);
  __syncthreads();
  u16 tmp[16];
#pragma unroll
  for (int i = 0; i < 16; i++) tmp[i] = t[c0 + i][row];
  u16* dst = vT + ((size_t)bh * 64 + row) * SQ + s0 + c0;
  *(short8*)dst = *(short8*)&tmp[0];
  *(short8*)(dst + 8) = *(short8*)&tmp[8];
}

// ---------------- GEMM: C[M,N] = A[M,K](bf16) @ Bt[N,K]^T(bf16) ----------------
// EPI 0: write f32 C row-major (ldc=1024). EPI 1: scatter qkv bf16 into [B,H,S,64].
template <int EPI>
__global__ __launch_bounds__(256) void k_gemm(const u16* __restrict__ A, const u16* __restrict__ Bt,
                                              float* __restrict__ Cf, u16* __restrict__ qb,
                                              u16* __restrict__ kb, u16* __restrict__ vb, int K) {
  __shared__ u16 lA[128 * 32];
  __shared__ u16 lB[128 * 32];
  int tid = threadIdx.x, w = tid >> 6, l = tid & 63;
  int wm = w >> 1, wn = w & 1;
  int tm = blockIdx.x, tn = blockIdx.y;
  int li = l & 15, lg = l >> 4;
  const u16* gA = A + (size_t)tm * 128 * K;
  const u16* gB = Bt + (size_t)tn * 128 * K;
  f32x4 acc[4][4];
#pragma unroll
  for (int i = 0; i < 4; i++)
#pragma unroll
    for (int j = 0; j < 4; j++) acc[i][j] = (f32x4){0.f, 0.f, 0.f, 0.f};
  int c0 = w, c1 = w + 4;
  int srow0 = c0 * 16 + (l >> 2), srow1 = c1 * 16 + (l >> 2);
  int scol = (l & 3) * 8;
  for (int kt = 0; kt < K; kt += 32) {
    __syncthreads();
    gload_lds16(gA + (size_t)srow0 * K + kt + scol, &lA[c0 * 512]);
    gload_lds16(gA + (size_t)srow1 * K + kt + scol, &lA[c1 * 512]);
    gload_lds16(gB + (size_t)srow0 * K + kt + scol, &lB[c0 * 512]);
    gload_lds16(gB + (size_t)srow1 * K + kt + scol, &lB[c1 * 512]);
    __syncthreads();
    short8 af[4], bfr[4];
#pragma unroll
    for (int mf = 0; mf < 4; ++mf) af[mf] = *(const short8*)&lA[(wm * 64 + mf * 16 + li) * 32 + lg * 8];
#pragma unroll
    for (int nf = 0; nf < 4; ++nf) bfr[nf] = *(const short8*)&lB[(wn * 64 + nf * 16 + li) * 32 + lg * 8];
#pragma unroll
    for (int mf = 0; mf < 4; ++mf)
#pragma unroll
      for (int nf = 0; nf < 4; ++nf)
        acc[mf][nf] = __builtin_amdgcn_mfma_f32_16x16x32_bf16(af[mf], bfr[nf], acc[mf][nf], 0, 0, 0);
  }
#pragma unroll
  for (int mf = 0; mf < 4; ++mf) {
    int mg0 = tm * 128 + wm * 64 + mf * 16 + lg * 4;
#pragma unroll
    for (int nf = 0; nf < 4; ++nf) {
      int ng = tn * 128 + wn * 64 + nf * 16 + li;
#pragma unroll
      for (int r = 0; r < 4; ++r) {
        float val = acc[mf][nf][r];
        int mg = mg0 + r;
        if (EPI == 0) {
          Cf[(size_t)mg * 1024 + ng] = val;
        } else {
          int b = mg >> 11, s = mg & 2047;
          int which = ng >> 10, hd6 = ng & 1023;
          int h = hd6 >> 6, d = hd6 & 63;
          u16* dst = which == 0 ? qb : (which == 1 ? kb : vb);
          dst[((((size_t)b * HQ + h) * SQ + s) << 6) + d] = f2bf(val);
        }
      }
    }
  }
}

// ---------------- flash attention ----------------
// grid (32 qblocks, 64 bh), 4 waves x 16 q rows, KBLK=64.
__global__ __launch_bounds__(256) void k_flash(const u16* __restrict__ Q, const u16* __restrict__ Kb,
                                               const u16* __restrict__ VT, const int* __restrict__ mask,
                                               u16* __restrict__ O) {
  __shared__ u16 Kl[64][72];
  __shared__ u16 Vl[64][72];
  __shared__ u16 Pl[4][16][72];
  __shared__ float biasl[64];
  int qb = blockIdx.x, bh = blockIdx.y;
  int b = bh >> 4, h = bh & 15;
  int tid = threadIdx.x, w = tid >> 6, l = tid & 63;
  int lg = l >> 4, li = l & 15;
  const u16* qp = Q + ((size_t)bh * SQ + qb * 64 + w * 16 + li) * 64 + lg * 8;
  short8 qf0 = *(const short8*)qp;
  short8 qf1 = *(const short8*)(qp + 32);
  f32x4 oacc[4];
#pragma unroll
  for (int f = 0; f < 4; ++f) oacc[f] = (f32x4){0.f, 0.f, 0.f, 0.f};
  float mrow[4] = {-INFINITY, -INFINITY, -INFINITY, -INFINITY};
  float lrow[4] = {0.f, 0.f, 0.f, 0.f};
  int srow = tid >> 2, sc0 = (tid & 3) * 16;
  for (int kt = 0; kt <= qb; ++kt) {
    __syncthreads();
    {
      const u16* gk = Kb + ((size_t)bh * SQ + kt * 64 + srow) * 64 + sc0;
      *(short8*)&Kl[srow][sc0] = *(const short8*)gk;
      *(short8*)&Kl[srow][sc0 + 8] = *(const short8*)(gk + 8);
      const u16* gv = VT + ((size_t)bh * 64 + srow) * SQ + kt * 64 + sc0;
      *(short8*)&Vl[srow][sc0] = *(const short8*)gv;
      *(short8*)&Vl[srow][sc0 + 8] = *(const short8*)(gv + 8);
      if (tid < 64) biasl[tid] = mask[b * SQ + kt * 64 + tid] ? 0.0f : -INFINITY;
    }
    __syncthreads();
    f32x4 sc[4];
#pragma unroll
    for (int f = 0; f < 4; ++f) sc[f] = (f32x4){0.f, 0.f, 0.f, 0.f};
#pragma unroll
    for (int f = 0; f < 4; ++f) {
      short8 kf0 = *(const short8*)&Kl[f * 16 + li][lg * 8];
      sc[f] = __builtin_amdgcn_mfma_f32_16x16x32_bf16(qf0, kf0, sc[f], 0, 0, 0);
      short8 kf1 = *(const short8*)&Kl[f * 16 + li][32 + lg * 8];
      sc[f] = __builtin_amdgcn_mfma_f32_16x16x32_bf16(qf1, kf1, sc[f], 0, 0, 0);
    }
    int qg = qb * 64 + w * 16 + lg * 4;
#pragma unroll
    for (int f = 0; f < 4; ++f) {
      int kg = kt * 64 + f * 16 + li;
      float bias = biasl[f * 16 + li];
#pragma unroll
      for (int r = 0; r < 4; ++r) {
        float vvv = sc[f][r] + bias;
        if (kg > qg + r) vvv = -INFINITY;
        sc[f][r] = vvv;
      }
    }
#pragma unroll
    for (int r = 0; r < 4; ++r) {
      float mt = fmaxf(fmaxf(sc[0][r], sc[1][r]), fmaxf(sc[2][r], sc[3][r]));
      mt = fmaxf(mt, __shfl_xor(mt, 1));
      mt = fmaxf(mt, __shfl_xor(mt, 2));
      mt = fmaxf(mt, __shfl_xor(mt, 4));
      mt = fmaxf(mt, __shfl_xor(mt, 8));
      float mn = fmaxf(mrow[r], mt);
      float alpha = __expf(mrow[r] - mn);
      mrow[r] = mn;
      float ps = 0.f;
#pragma unroll
      for (int f = 0; f < 4; ++f) {
        float p = __expf(sc[f][r] - mn);
        sc[f][r] = p;
        ps += p;
      }
      ps += __shfl_xor(ps, 1);
      ps += __shfl_xor(ps, 2);
      ps += __shfl_xor(ps, 4);
      ps += __shfl_xor(ps, 8);
      lrow[r] = lrow[r] * alpha + ps;
#pragma unroll
      for (int f = 0; f < 4; ++f) oacc[f][r] *= alpha;
    }
#pragma unroll
    for (int r = 0; r < 4; ++r)
#pragma unroll
      for (int f = 0; f < 4; ++f) Pl[w][lg * 4 + r][f * 16 + li] = f2bf(sc[f][r]);
    asm volatile("s_waitcnt lgkmcnt(0)" ::: "memory");
    __builtin_amdgcn_sched_barrier(0);
    short8 pa0 = *(const short8*)&Pl[w][li][lg * 8];
    short8 pa1 = *(const short8*)&Pl[w][li][32 + lg * 8];
#pragma unroll
    for (int f = 0; f < 4; ++f) {
      short8 vf0 = *(const short8*)&Vl[f * 16 + li][lg * 8];
      oacc[f] = __builtin_amdgcn_mfma_f32_16x16x32_bf16(pa0, vf0, oacc[f], 0, 0, 0);
      short8 vf1 = *(const short8*)&Vl[f * 16 + li][32 + lg * 8];
      oacc[f] = __builtin_amdgcn_mfma_f32_16x16x32_bf16(pa1, vf1, oacc[f], 0, 0, 0);
    }
  }
  int sg = qb * 64 + w * 16 + lg * 4;
#pragma unroll
  for (int r = 0; r < 4; ++r) {
    float inv = 1.0f / lrow[r];
#pragma unroll
    for (int f = 0; f < 4; ++f)
      O[((size_t)b * SQ + sg + r) * DQ + h * 64 + f * 16 + li] = f2bf(oacc[f][r] * inv);
  }
}

extern "C" void kernel_launch(void* const* d_in, const int* in_sizes, int n_in,
                              void* d_out, int out_size, void* d_ws, size_t ws_size,
                              hipStream_t stream) {
  const float* x = (const float*)d_in[0];
  const int* mask = (const int*)d_in[1];
  const float* wqkv = (const float*)d_in[2];
  const float* wout = (const float*)d_in[3];
  float* out = (float*)d_out;
  char* ws = (char*)d_ws;

  u16* xb    = (u16*)(ws + 0);           // 16 MB
  u16* wqkvT = (u16*)(ws + 16777216);    // 6 MB  [3072][1024]
  u16* woutT = (u16*)(ws + 23068672);    // 2 MB  [1024][1024]
  u16* qbuf  = (u16*)(ws + 25165824);    // 16 MB [bh][S][64]
  u16* kbuf  = (u16*)(ws + 41943040);    // 16 MB
  u16* vbuf  = (u16*)(ws + 58720256);    // 16 MB
  u16* vT    = (u16*)(ws + 75497472);    // 16 MB [bh][64][S]
  u16* attnb = (u16*)(ws + 92274688);    // 16 MB [B*S][1024]
  float* tab = (float*)(ws + 109051904); // 512 KB

  k_rope_table<<<256, 256, 0, stream>>>(tab);
  k_cvt<<<8192, 256, 0, stream>>>(x, xb, 2097152);
  k_transpose_cvt<<<dim3(96, 32), 256, 0, stream>>>(wqkv, wqkvT, 1024, 3072);
  k_transpose_cvt<<<dim3(32, 32), 256, 0, stream>>>(wout, woutT, 1024, 1024);
  k_gemm<1><<<dim3(64, 24), 256, 0, stream>>>(xb, wqkvT, nullptr, qbuf, kbuf, vbuf, 1024);
  k_rope<<<32768, 256, 0, stream>>>(qbuf, kbuf, tab);
  k_transpose_v<<<dim3(32, 64), 256, 0, stream>>>(vbuf, vT);
  k_flash<<<dim3(32, 64), 256, 0, stream>>>(qbuf, kbuf, vT, mask, attnb);
  k_gemm<0><<<dim3(64, 8), 256, 0, stream>>>(attnb, woutT, out, nullptr, nullptr, nullptr, 1024);
}